// Round 12
// baseline (403.260 us; speedup 1.0000x reference)
//
#include <hip/hip_runtime.h>
#include <hip/hip_bf16.h>

// GAT (3 layers) + MLP head. N=50000, E=800000 (+N self loops), D=128, H=256, C=6.
// Round 12: k_mfma_mlp rewritten LDS-free single-pass. R11's two-half h-loop
// spilled its accumulators (WRITE_SIZE 52.8MB for a 1.2MB output, VALUBusy 6%).
// Now: acc[16] f32x4 covers all 256 cols in one pass; A/B fragments read
// directly from global/L2 (Wm1t is 64KB, L2-resident); W2+bias in 7KB LDS;
// pc[4][6] only live in the epilogue. No barriers in the MFMA loop, no spill.

typedef _Float16 h4 __attribute__((ext_vector_type(4)));
typedef _Float16 half8 __attribute__((ext_vector_type(8)));
typedef float f32x4 __attribute__((ext_vector_type(4)));

#define LDA 136   // padded fp16 row stride for MFMA staging (gat kernel)
#define DCAP 256  // max degree handled by the LDS fast path

__global__ __launch_bounds__(256) void k_hist(const int* __restrict__ ei, int* __restrict__ deg,
                                              int* __restrict__ rank, int E_, int N_) {
    int e = blockIdx.x * 256 + threadIdx.x;
    int total = E_ + N_;
    if (e >= total) return;
    int d = (e < E_) ? ei[E_ + e] : (e - E_);
    rank[e] = atomicAdd(&deg[d], 1);
}

__device__ inline int block_incl_scan(int v, int* wsum) {
    int lane = threadIdx.x & 63, wid = threadIdx.x >> 6;
    #pragma unroll
    for (int d = 1; d < 64; d <<= 1) {
        int t = __shfl_up(v, d);
        if (lane >= d) v += t;
    }
    if (lane == 63) wsum[wid] = v;
    __syncthreads();
    if (wid == 0 && lane < 4) {
        int s = wsum[lane];
        #pragma unroll
        for (int d = 1; d < 4; d <<= 1) {
            int t = __shfl_up(s, d);
            if (lane >= d) s += t;
        }
        wsum[lane] = s;
    }
    __syncthreads();
    if (wid > 0) v += wsum[wid - 1];
    return v;
}

__global__ __launch_bounds__(256) void k_bsum(const int* __restrict__ deg, int* __restrict__ bsum, int n) {
    __shared__ int wsum[4];
    int i = blockIdx.x * 256 + threadIdx.x;
    int v = (i < n) ? deg[i] : 0;
    int lane = threadIdx.x & 63, wid = threadIdx.x >> 6;
    #pragma unroll
    for (int d = 32; d > 0; d >>= 1) v += __shfl_down(v, d);
    if (lane == 0) wsum[wid] = v;
    __syncthreads();
    if (threadIdx.x == 0) bsum[blockIdx.x] = wsum[0] + wsum[1] + wsum[2] + wsum[3];
}

__global__ __launch_bounds__(256) void k_scanb(int* __restrict__ bsum, int nb) {
    __shared__ int wsum[4];
    int i = threadIdx.x;
    int orig = (i < nb) ? bsum[i] : 0;
    int v = block_incl_scan(orig, wsum);
    if (i < nb) bsum[i] = v - orig;
}

__global__ __launch_bounds__(256) void k_off(const int* __restrict__ deg, const int* __restrict__ bsum,
                                             int* __restrict__ off, int n) {
    __shared__ int wsum[4];
    int i = blockIdx.x * 256 + threadIdx.x;
    int orig = (i < n) ? deg[i] : 0;
    int v = block_incl_scan(orig, wsum);
    int base = bsum[blockIdx.x];
    if (i < n) off[i] = base + v - orig;
    if (i == n - 1) off[n] = base + v;
}

__global__ __launch_bounds__(256) void k_scatter(const int* __restrict__ ei, const int* __restrict__ off,
                                                 const int* __restrict__ rank, int* __restrict__ csrc,
                                                 int E_, int N_) {
    int e = blockIdx.x * 256 + threadIdx.x;
    int total = E_ + N_;
    if (e >= total) return;
    int s, d;
    if (e < E_) { s = ei[e]; d = ei[E_ + e]; }
    else        { s = e - E_; d = e - E_; }
    csrc[off[d] + rank[e]] = s;
}

// fused prep: x->fp16, W0..W2 transpose->fp16, Wm1 transpose->fp16
__global__ __launch_bounds__(256) void k_prep(const float* __restrict__ x, _Float16* __restrict__ xh,
        const float* __restrict__ W0, const float* __restrict__ W1, const float* __restrict__ W2,
        _Float16* __restrict__ Wt3, const float* __restrict__ Wm1, _Float16* __restrict__ Wm1t, int n4) {
    int i = blockIdx.x * 256 + threadIdx.x;
    if (i < n4) {
        float4 v = ((const float4*)x)[i];
        h4 o;
        o.x = (_Float16)v.x; o.y = (_Float16)v.y; o.z = (_Float16)v.z; o.w = (_Float16)v.w;
        ((h4*)xh)[i] = o;
        return;
    }
    int t = i - n4;
    if (t < 3 * 16384) {
        int seg = t >> 14;
        int j = t & 16383;
        const float* W = (seg == 0) ? W0 : (seg == 1) ? W1 : W2;
        int nn = j >> 7, k = j & 127;
        Wt3[t] = (_Float16)W[k * 128 + nn];
        return;
    }
    t -= 3 * 16384;
    if (t < 32768) {
        int nn = t >> 7, k = t & 127;
        Wm1t[t] = (_Float16)Wm1[k * 256 + nn];
    }
}

// Layer GEMM via MFMA: hh[M x 128](fp16) = A16[M x 128] @ W + fused alpha dots.
__global__ __launch_bounds__(256, 3) void k_mfma_gat(const _Float16* __restrict__ A16,
        const _Float16* __restrict__ Wt, const float* __restrict__ asrc, const float* __restrict__ adst,
        _Float16* __restrict__ hh, float* __restrict__ avs, float* __restrict__ avd, int M) {
    __shared__ _Float16 As[64 * LDA];
    __shared__ _Float16 Bs[128 * LDA];
    int tid = threadIdx.x;
    int bm = blockIdx.x * 64;
    #pragma unroll
    for (int i = 0; i < 4; ++i) {
        int idx = i * 256 + tid;
        int row = idx >> 4, c16 = idx & 15;
        int gr = bm + row;
        uint4 v = make_uint4(0u, 0u, 0u, 0u);
        if (gr < M) v = *(const uint4*)(A16 + (size_t)gr * 128 + c16 * 8);
        *(uint4*)&As[row * LDA + c16 * 8] = v;
    }
    #pragma unroll
    for (int i = 0; i < 8; ++i) {
        int idx = i * 256 + tid;
        int row = idx >> 4, c16 = idx & 15;
        *(uint4*)&Bs[row * LDA + c16 * 8] = *(const uint4*)(Wt + (size_t)row * 128 + c16 * 8);
    }
    __syncthreads();
    int w = tid >> 6, l = tid & 63;
    int quad = l >> 4, cl = l & 15;
    f32x4 acc[8] = {};
    const _Float16* ap = &As[(w * 16 + cl) * LDA + quad * 8];
    #pragma unroll
    for (int kt = 0; kt < 4; ++kt) {
        half8 a = *(const half8*)(ap + kt * 32);
        #pragma unroll
        for (int ct = 0; ct < 8; ++ct) {
            half8 b = *(const half8*)&Bs[(ct * 16 + cl) * LDA + kt * 32 + quad * 8];
            acc[ct] = __builtin_amdgcn_mfma_f32_16x16x32_f16(a, b, acc[ct], 0, 0, 0);
        }
    }
    float sa[8], da[8];
    #pragma unroll
    for (int ct = 0; ct < 8; ++ct) { sa[ct] = asrc[ct * 16 + cl]; da[ct] = adst[ct * 16 + cl]; }
    #pragma unroll
    for (int r = 0; r < 4; ++r) {
        int row = bm + w * 16 + quad * 4 + r;
        bool ok = row < M;
        float ps = 0.f, pd = 0.f;
        #pragma unroll
        for (int ct = 0; ct < 8; ++ct) {
            float v = acc[ct][r];
            if (ok) hh[(size_t)row * 128 + ct * 16 + cl] = (_Float16)v;
            ps += v * sa[ct];
            pd += v * da[ct];
        }
        #pragma unroll
        for (int msk = 1; msk <= 8; msk <<= 1) { ps += __shfl_xor(ps, msk); pd += __shfl_xor(pd, msk); }
        if (cl == 0 && ok) { avs[row] = ps; avd[row] = pd; }
    }
}

// Fused MLP, LDS-free single-pass: out[M x 6] = relu(A16 @ Wm1 + bm1) @ Wm2 + bm2.
// One block per 64 rows; acc[16] covers all 256 H-cols; A/B frags direct from
// global (Wm1t = 64KB, L2-resident). W2/bias/b2 in 7KB LDS. No barriers in loop.
__global__ __launch_bounds__(256, 4) void k_mfma_mlp(const _Float16* __restrict__ A16,
        const _Float16* __restrict__ Wt, const float* __restrict__ bias,
        const float* __restrict__ W2, const float* __restrict__ b2,
        float* __restrict__ out, int M) {
    __shared__ float W2s[256 * 6];
    __shared__ float bss[256];
    int tid = threadIdx.x;
    #pragma unroll
    for (int i = 0; i < 6; ++i) W2s[i * 256 + tid] = W2[i * 256 + tid];
    bss[tid] = bias[tid];
    __syncthreads();
    int w = tid >> 6, l = tid & 63;
    int quad = l >> 4, cl = l & 15;
    int bm = blockIdx.x * 64;
    int arow = bm + w * 16 + cl;
    if (arow >= M) arow = M - 1;          // clamp; results discarded at store
    const _Float16* ap = A16 + (size_t)arow * 128 + quad * 8;
    f32x4 acc[16];
    #pragma unroll
    for (int i = 0; i < 16; ++i) acc[i] = (f32x4){0.f, 0.f, 0.f, 0.f};
    #pragma unroll
    for (int kt = 0; kt < 4; ++kt) {
        half8 av = *(const half8*)(ap + kt * 32);
        const _Float16* bp = Wt + (size_t)cl * 128 + kt * 32 + quad * 8;
        #pragma unroll
        for (int hc = 0; hc < 16; ++hc) {
            half8 bv = *(const half8*)(bp + (size_t)hc * 16 * 128);
            acc[hc] = __builtin_amdgcn_mfma_f32_16x16x32_f16(av, bv, acc[hc], 0, 0, 0);
        }
    }
    float pc[4][6] = {};
    #pragma unroll
    for (int hc = 0; hc < 16; ++hc) {
        int col = hc * 16 + cl;
        float bb = bss[col];
        float w0 = W2s[col * 6 + 0], w1 = W2s[col * 6 + 1], w2v = W2s[col * 6 + 2];
        float w3 = W2s[col * 6 + 3], w4 = W2s[col * 6 + 4], w5 = W2s[col * 6 + 5];
        #pragma unroll
        for (int r = 0; r < 4; ++r) {
            float v = fmaxf(acc[hc][r] + bb, 0.f);
            pc[r][0] += v * w0; pc[r][1] += v * w1; pc[r][2] += v * w2v;
            pc[r][3] += v * w3; pc[r][4] += v * w4; pc[r][5] += v * w5;
        }
    }
    #pragma unroll
    for (int r = 0; r < 4; ++r) {
        #pragma unroll
        for (int msk = 1; msk <= 8; msk <<= 1) {
            #pragma unroll
            for (int c = 0; c < 6; ++c) pc[r][c] += __shfl_xor(pc[r][c], msk);
        }
        int row = bm + w * 16 + quad * 4 + r;
        if (cl == 0 && row < M) {
            #pragma unroll
            for (int c = 0; c < 6; ++c) out[(size_t)row * 6 + c] = pc[r][c] + b2[c];
        }
    }
}

// one wave per dst node. Pass 1 (64-lane edge-parallel): score->LDS, max, exp->LDS, sum
// (register fast path for deg<=64). Pass 2: 16-lane group per edge, half8 gathers, 4x unroll.
__global__ __launch_bounds__(256) void k_aggregate(const _Float16* __restrict__ hh, const int* __restrict__ off,
                                                   const int* __restrict__ csrc, const float* __restrict__ avs,
                                                   const float* __restrict__ avd, const float* __restrict__ bias,
                                                   _Float16* __restrict__ outh, int n) {
    __shared__ float ew[4][DCAP];
    int wv = threadIdx.x >> 6;
    int w = (blockIdx.x * 256 + threadIdx.x) >> 6;
    int lane = threadIdx.x & 63;
    if (w >= n) return;
    int grp = lane >> 4;
    int gl = lane & 15;
    int beg = off[w], end = off[w + 1];
    int deg = end - beg;
    float adn = avd[w];
    float accf[8] = {};
    float ssum = 0.f;

    if (deg <= DCAP) {
        if (deg <= 64) {
            int j = beg + lane;
            float sc = -1e30f;
            if (j < end) {
                sc = avs[csrc[j]] + adn;
                sc = (sc < 0.f) ? 0.2f * sc : sc;
            }
            float m = sc;
            #pragma unroll
            for (int d = 32; d > 0; d >>= 1) m = fmaxf(m, __shfl_xor(m, d));
            float e = 0.f;
            if (j < end) {
                e = __expf(sc - m);
                ew[wv][lane] = e;
            }
            float ss = e;
            #pragma unroll
            for (int d = 32; d > 0; d >>= 1) ss += __shfl_xor(ss, d);
            ssum = ss;
        } else {
            float m = -1e30f;
            for (int j = beg + lane; j < end; j += 64) {
                float sc = avs[csrc[j]] + adn;
                sc = (sc < 0.f) ? 0.2f * sc : sc;
                ew[wv][j - beg] = sc;
                m = fmaxf(m, sc);
            }
            #pragma unroll
            for (int d = 32; d > 0; d >>= 1) m = fmaxf(m, __shfl_xor(m, d));
            float ss = 0.f;
            for (int j = beg + lane; j < end; j += 64) {
                float e = __expf(ew[wv][j - beg] - m);
                ew[wv][j - beg] = e;
                ss += e;
            }
            #pragma unroll
            for (int d = 32; d > 0; d >>= 1) ss += __shfl_xor(ss, d);
            ssum = ss;
        }
        int j = beg + grp;
        for (; j + 12 < end; j += 16) {
            int s0 = csrc[j], s1 = csrc[j + 4], s2 = csrc[j + 8], s3 = csrc[j + 12];
            half8 v0 = *((const half8*)(hh + (size_t)s0 * 128) + gl);
            half8 v1 = *((const half8*)(hh + (size_t)s1 * 128) + gl);
            half8 v2 = *((const half8*)(hh + (size_t)s2 * 128) + gl);
            half8 v3 = *((const half8*)(hh + (size_t)s3 * 128) + gl);
            float e0 = ew[wv][j - beg],     e1 = ew[wv][j + 4 - beg];
            float e2 = ew[wv][j + 8 - beg], e3 = ew[wv][j + 12 - beg];
            #pragma unroll
            for (int f = 0; f < 8; ++f)
                accf[f] += (e0 * (float)v0[f] + e1 * (float)v1[f])
                         + (e2 * (float)v2[f] + e3 * (float)v3[f]);
        }
        for (; j < end; j += 4) {
            int s0 = csrc[j];
            half8 v0 = *((const half8*)(hh + (size_t)s0 * 128) + gl);
            float e0 = ew[wv][j - beg];
            #pragma unroll
            for (int f = 0; f < 8; ++f) accf[f] += e0 * (float)v0[f];
        }
    } else {
        float m = -1e30f;
        for (int j = beg + lane; j < end; j += 64) {
            float sc = avs[csrc[j]] + adn;
            sc = (sc < 0.f) ? 0.2f * sc : sc;
            m = fmaxf(m, sc);
        }
        #pragma unroll
        for (int d = 32; d > 0; d >>= 1) m = fmaxf(m, __shfl_xor(m, d));
        float ss = 0.f;
        for (int j = beg + grp; j < end; j += 4) {
            int s0 = csrc[j];
            half8 v0 = *((const half8*)(hh + (size_t)s0 * 128) + gl);
            float sc = avs[s0] + adn; sc = (sc < 0.f) ? 0.2f * sc : sc;
            float e0 = __expf(sc - m);
            ss += e0;
            #pragma unroll
            for (int f = 0; f < 8; ++f) accf[f] += e0 * (float)v0[f];
        }
        ssum = ss;
    }
    #pragma unroll
    for (int f = 0; f < 8; ++f) {
        accf[f] += __shfl_xor(accf[f], 16);
        accf[f] += __shfl_xor(accf[f], 32);
    }
    if (deg > DCAP) {
        ssum += __shfl_xor(ssum, 16);
        ssum += __shfl_xor(ssum, 32);
    }
    if (grp == 0) {
        float inv = 1.f / ssum;
        float4 b0 = ((const float4*)bias)[gl * 2];
        float4 b1 = ((const float4*)bias)[gl * 2 + 1];
        half8 o;
        o[0] = (_Float16)fmaxf(accf[0] * inv + b0.x, 0.f);
        o[1] = (_Float16)fmaxf(accf[1] * inv + b0.y, 0.f);
        o[2] = (_Float16)fmaxf(accf[2] * inv + b0.z, 0.f);
        o[3] = (_Float16)fmaxf(accf[3] * inv + b0.w, 0.f);
        o[4] = (_Float16)fmaxf(accf[4] * inv + b1.x, 0.f);
        o[5] = (_Float16)fmaxf(accf[5] * inv + b1.y, 0.f);
        o[6] = (_Float16)fmaxf(accf[6] * inv + b1.z, 0.f);
        o[7] = (_Float16)fmaxf(accf[7] * inv + b1.w, 0.f);
        *((half8*)(outh + (size_t)w * 128) + gl) = o;
    }
}

extern "C" void kernel_launch(void* const* d_in, const int* in_sizes, int n_in,
                              void* d_out, int out_size, void* d_ws, size_t ws_size,
                              hipStream_t stream) {
    const float* x   = (const float*)d_in[0];
    const int*   ei  = (const int*)d_in[1];
    const float* W[3]    = {(const float*)d_in[2], (const float*)d_in[6], (const float*)d_in[10]};
    const float* bL[3]   = {(const float*)d_in[3], (const float*)d_in[7], (const float*)d_in[11]};
    const float* asr[3]  = {(const float*)d_in[4], (const float*)d_in[8], (const float*)d_in[12]};
    const float* ads[3]  = {(const float*)d_in[5], (const float*)d_in[9], (const float*)d_in[13]};
    const float* Wm1 = (const float*)d_in[14];
    const float* bm1 = (const float*)d_in[15];
    const float* Wm2 = (const float*)d_in[16];
    const float* bm2 = (const float*)d_in[17];
    float* out = (float*)d_out;

    const int N_ = in_sizes[0] / 128;
    const int E_ = in_sizes[1] / 2;
    const int TOT = E_ + N_;
    const int NB = (N_ + 255) / 256;

    char* p = (char*)d_ws;
    auto alloc = [&](size_t bytes) { void* r = (void*)p; p += (bytes + 255) & ~(size_t)255; return r; };
    size_t npad = ((size_t)N_ * 4 + 255) & ~(size_t)255;
    int*   deg  = (int*)alloc(npad);
    int*   off  = (int*)alloc((size_t)(N_ + 1) * 4);
    int*   bsum = (int*)alloc((size_t)(NB + 1) * 4);
    int*   rank = (int*)alloc((size_t)TOT * 4);
    int*   csrc = (int*)alloc((size_t)TOT * 4);
    float* avs  = (float*)alloc((size_t)N_ * 4);
    float* avd  = (float*)alloc((size_t)N_ * 4);
    _Float16* Wt3  = (_Float16*)alloc(3 * 16384 * 2);
    _Float16* Wm1t = (_Float16*)alloc(32768 * 2);
    _Float16* xh   = (_Float16*)alloc((size_t)N_ * 128 * 2);
    _Float16* agg  = (_Float16*)alloc((size_t)N_ * 128 * 2);
    _Float16* hh   = (_Float16*)alloc((size_t)N_ * 128 * 2);

    // ---- CSR build + prep ----
    hipMemsetAsync(deg, 0, npad, stream);
    k_hist<<<(TOT + 255) / 256, 256, 0, stream>>>(ei, deg, rank, E_, N_);
    k_bsum<<<NB, 256, 0, stream>>>(deg, bsum, N_);
    k_scanb<<<1, 256, 0, stream>>>(bsum, NB);
    k_off<<<NB, 256, 0, stream>>>(deg, bsum, off, N_);
    k_scatter<<<(TOT + 255) / 256, 256, 0, stream>>>(ei, off, rank, csrc, E_, N_);
    int n4 = N_ * 32;
    int prep_items = n4 + 3 * 16384 + 32768;
    k_prep<<<(prep_items + 255) / 256, 256, 0, stream>>>(x, xh, W[0], W[1], W[2], Wt3, Wm1, Wm1t, n4);

    const int wave_blocks = (N_ + 3) / 4;
    const int gat_blocks = (N_ + 63) / 64;

    // ---- 3 GAT layers ----
    const _Float16* cur_in = xh;
    for (int l = 0; l < 3; ++l) {
        k_mfma_gat<<<gat_blocks, 256, 0, stream>>>(cur_in, Wt3 + l * 16384, asr[l], ads[l],
                                                   hh, avs, avd, N_);
        k_aggregate<<<wave_blocks, 256, 0, stream>>>(hh, off, csrc, avs, avd, bL[l], agg, N_);
        cur_in = agg;
    }

    // ---- fused MLP head (LDS-free, no atomics, no spill) ----
    k_mfma_mlp<<<gat_blocks, 256, 0, stream>>>(agg, Wm1t, bm1, Wm2, bm2, out, N_);
}

// Round 13
// 351.577 us; speedup vs baseline: 1.1470x; 1.1470x over previous
//
#include <hip/hip_runtime.h>
#include <hip/hip_bf16.h>

// GAT (3 layers) + MLP head. N=50000, E=800000 (+N self loops), D=128, H=256, C=6.
// Round 13: k_mfma_mlp with acc[8] ONLY (32 VGPRs). R11/R12 both spilled
// (acc[16]/two-half accumulators -> 50-230MB scratch traffic, allocator pins
// at the 64-VGPR occupancy step). Now: block = 32 rows; wave = (row-group,
// col-half); per-wave acc[8] + pc[4][6]; 1.5KB LDS cross-wave combine; plain
// coalesced store. No atomics, no mid buffer, nothing >50 VGPRs live.

typedef _Float16 h4 __attribute__((ext_vector_type(4)));
typedef _Float16 half8 __attribute__((ext_vector_type(8)));
typedef float f32x4 __attribute__((ext_vector_type(4)));

#define LDA 136   // padded fp16 row stride for MFMA staging (gat kernel)
#define DCAP 256  // max degree handled by the LDS fast path

__global__ __launch_bounds__(256) void k_hist(const int* __restrict__ ei, int* __restrict__ deg,
                                              int* __restrict__ rank, int E_, int N_) {
    int e = blockIdx.x * 256 + threadIdx.x;
    int total = E_ + N_;
    if (e >= total) return;
    int d = (e < E_) ? ei[E_ + e] : (e - E_);
    rank[e] = atomicAdd(&deg[d], 1);
}

__device__ inline int block_incl_scan(int v, int* wsum) {
    int lane = threadIdx.x & 63, wid = threadIdx.x >> 6;
    #pragma unroll
    for (int d = 1; d < 64; d <<= 1) {
        int t = __shfl_up(v, d);
        if (lane >= d) v += t;
    }
    if (lane == 63) wsum[wid] = v;
    __syncthreads();
    if (wid == 0 && lane < 4) {
        int s = wsum[lane];
        #pragma unroll
        for (int d = 1; d < 4; d <<= 1) {
            int t = __shfl_up(s, d);
            if (lane >= d) s += t;
        }
        wsum[lane] = s;
    }
    __syncthreads();
    if (wid > 0) v += wsum[wid - 1];
    return v;
}

__global__ __launch_bounds__(256) void k_bsum(const int* __restrict__ deg, int* __restrict__ bsum, int n) {
    __shared__ int wsum[4];
    int i = blockIdx.x * 256 + threadIdx.x;
    int v = (i < n) ? deg[i] : 0;
    int lane = threadIdx.x & 63, wid = threadIdx.x >> 6;
    #pragma unroll
    for (int d = 32; d > 0; d >>= 1) v += __shfl_down(v, d);
    if (lane == 0) wsum[wid] = v;
    __syncthreads();
    if (threadIdx.x == 0) bsum[blockIdx.x] = wsum[0] + wsum[1] + wsum[2] + wsum[3];
}

__global__ __launch_bounds__(256) void k_scanb(int* __restrict__ bsum, int nb) {
    __shared__ int wsum[4];
    int i = threadIdx.x;
    int orig = (i < nb) ? bsum[i] : 0;
    int v = block_incl_scan(orig, wsum);
    if (i < nb) bsum[i] = v - orig;
}

__global__ __launch_bounds__(256) void k_off(const int* __restrict__ deg, const int* __restrict__ bsum,
                                             int* __restrict__ off, int n) {
    __shared__ int wsum[4];
    int i = blockIdx.x * 256 + threadIdx.x;
    int orig = (i < n) ? deg[i] : 0;
    int v = block_incl_scan(orig, wsum);
    int base = bsum[blockIdx.x];
    if (i < n) off[i] = base + v - orig;
    if (i == n - 1) off[n] = base + v;
}

__global__ __launch_bounds__(256) void k_scatter(const int* __restrict__ ei, const int* __restrict__ off,
                                                 const int* __restrict__ rank, int* __restrict__ csrc,
                                                 int E_, int N_) {
    int e = blockIdx.x * 256 + threadIdx.x;
    int total = E_ + N_;
    if (e >= total) return;
    int s, d;
    if (e < E_) { s = ei[e]; d = ei[E_ + e]; }
    else        { s = e - E_; d = e - E_; }
    csrc[off[d] + rank[e]] = s;
}

// fused prep: x->fp16, W0..W2 transpose->fp16, Wm1 transpose->fp16
__global__ __launch_bounds__(256) void k_prep(const float* __restrict__ x, _Float16* __restrict__ xh,
        const float* __restrict__ W0, const float* __restrict__ W1, const float* __restrict__ W2,
        _Float16* __restrict__ Wt3, const float* __restrict__ Wm1, _Float16* __restrict__ Wm1t, int n4) {
    int i = blockIdx.x * 256 + threadIdx.x;
    if (i < n4) {
        float4 v = ((const float4*)x)[i];
        h4 o;
        o.x = (_Float16)v.x; o.y = (_Float16)v.y; o.z = (_Float16)v.z; o.w = (_Float16)v.w;
        ((h4*)xh)[i] = o;
        return;
    }
    int t = i - n4;
    if (t < 3 * 16384) {
        int seg = t >> 14;
        int j = t & 16383;
        const float* W = (seg == 0) ? W0 : (seg == 1) ? W1 : W2;
        int nn = j >> 7, k = j & 127;
        Wt3[t] = (_Float16)W[k * 128 + nn];
        return;
    }
    t -= 3 * 16384;
    if (t < 32768) {
        int nn = t >> 7, k = t & 127;
        Wm1t[t] = (_Float16)Wm1[k * 256 + nn];
    }
}

// Layer GEMM via MFMA: hh[M x 128](fp16) = A16[M x 128] @ W + fused alpha dots.
__global__ __launch_bounds__(256, 3) void k_mfma_gat(const _Float16* __restrict__ A16,
        const _Float16* __restrict__ Wt, const float* __restrict__ asrc, const float* __restrict__ adst,
        _Float16* __restrict__ hh, float* __restrict__ avs, float* __restrict__ avd, int M) {
    __shared__ _Float16 As[64 * LDA];
    __shared__ _Float16 Bs[128 * LDA];
    int tid = threadIdx.x;
    int bm = blockIdx.x * 64;
    #pragma unroll
    for (int i = 0; i < 4; ++i) {
        int idx = i * 256 + tid;
        int row = idx >> 4, c16 = idx & 15;
        int gr = bm + row;
        uint4 v = make_uint4(0u, 0u, 0u, 0u);
        if (gr < M) v = *(const uint4*)(A16 + (size_t)gr * 128 + c16 * 8);
        *(uint4*)&As[row * LDA + c16 * 8] = v;
    }
    #pragma unroll
    for (int i = 0; i < 8; ++i) {
        int idx = i * 256 + tid;
        int row = idx >> 4, c16 = idx & 15;
        *(uint4*)&Bs[row * LDA + c16 * 8] = *(const uint4*)(Wt + (size_t)row * 128 + c16 * 8);
    }
    __syncthreads();
    int w = tid >> 6, l = tid & 63;
    int quad = l >> 4, cl = l & 15;
    f32x4 acc[8] = {};
    const _Float16* ap = &As[(w * 16 + cl) * LDA + quad * 8];
    #pragma unroll
    for (int kt = 0; kt < 4; ++kt) {
        half8 a = *(const half8*)(ap + kt * 32);
        #pragma unroll
        for (int ct = 0; ct < 8; ++ct) {
            half8 b = *(const half8*)&Bs[(ct * 16 + cl) * LDA + kt * 32 + quad * 8];
            acc[ct] = __builtin_amdgcn_mfma_f32_16x16x32_f16(a, b, acc[ct], 0, 0, 0);
        }
    }
    float sa[8], da[8];
    #pragma unroll
    for (int ct = 0; ct < 8; ++ct) { sa[ct] = asrc[ct * 16 + cl]; da[ct] = adst[ct * 16 + cl]; }
    #pragma unroll
    for (int r = 0; r < 4; ++r) {
        int row = bm + w * 16 + quad * 4 + r;
        bool ok = row < M;
        float ps = 0.f, pd = 0.f;
        #pragma unroll
        for (int ct = 0; ct < 8; ++ct) {
            float v = acc[ct][r];
            if (ok) hh[(size_t)row * 128 + ct * 16 + cl] = (_Float16)v;
            ps += v * sa[ct];
            pd += v * da[ct];
        }
        #pragma unroll
        for (int msk = 1; msk <= 8; msk <<= 1) { ps += __shfl_xor(ps, msk); pd += __shfl_xor(pd, msk); }
        if (cl == 0 && ok) { avs[row] = ps; avd[row] = pd; }
    }
}

// Fused MLP, acc[8]-only: out[M x 6] = relu(A16 @ Wm1 + bm1) @ Wm2 + bm2.
// Block = 32 rows; wave w -> (row-group w>>1, col-half w&1). A/B frags direct
// from global/L2 (Wm1t = 64KB). Cross-wave combine via 1.5KB LDS, plain store.
__global__ __launch_bounds__(256) void k_mfma_mlp(const _Float16* __restrict__ A16,
        const _Float16* __restrict__ Wt, const float* __restrict__ bias,
        const float* __restrict__ W2, const float* __restrict__ b2,
        float* __restrict__ out, int M) {
    __shared__ float W2s[256 * 6];
    __shared__ float bss[256];
    __shared__ float comb[4][16][6];
    int tid = threadIdx.x;
    #pragma unroll
    for (int i = 0; i < 6; ++i) W2s[i * 256 + tid] = W2[i * 256 + tid];
    bss[tid] = bias[tid];
    __syncthreads();
    int w = tid >> 6, l = tid & 63;
    int quad = l >> 4, cl = l & 15;
    int rg = w >> 1;             // row-group 0/1
    int ch = w & 1;              // col-half 0/1
    int bm = blockIdx.x * 32 + rg * 16;
    int arow = bm + cl;
    int arc = (arow < M) ? arow : (M - 1);   // clamp; combine discards OOB rows
    const _Float16* ap = A16 + (size_t)arc * 128 + quad * 8;
    f32x4 acc[8];
    #pragma unroll
    for (int i = 0; i < 8; ++i) acc[i] = (f32x4){0.f, 0.f, 0.f, 0.f};
    #pragma unroll
    for (int kt = 0; kt < 4; ++kt) {
        half8 av = *(const half8*)(ap + kt * 32);
        const _Float16* bp = Wt + (size_t)(ch * 128 + cl) * 128 + kt * 32 + quad * 8;
        #pragma unroll
        for (int ct = 0; ct < 8; ++ct) {
            half8 bv = *(const half8*)(bp + (size_t)ct * 16 * 128);
            acc[ct] = __builtin_amdgcn_mfma_f32_16x16x32_f16(av, bv, acc[ct], 0, 0, 0);
        }
    }
    float pc[4][6] = {};
    #pragma unroll
    for (int ct = 0; ct < 8; ++ct) {
        int col = ch * 128 + ct * 16 + cl;
        float bb = bss[col];
        float w0 = W2s[col * 6 + 0], w1 = W2s[col * 6 + 1], w2v = W2s[col * 6 + 2];
        float w3 = W2s[col * 6 + 3], w4 = W2s[col * 6 + 4], w5 = W2s[col * 6 + 5];
        #pragma unroll
        for (int r = 0; r < 4; ++r) {
            float v = fmaxf(acc[ct][r] + bb, 0.f);
            pc[r][0] += v * w0; pc[r][1] += v * w1; pc[r][2] += v * w2v;
            pc[r][3] += v * w3; pc[r][4] += v * w4; pc[r][5] += v * w5;
        }
    }
    #pragma unroll
    for (int r = 0; r < 4; ++r) {
        #pragma unroll
        for (int msk = 1; msk <= 8; msk <<= 1) {
            #pragma unroll
            for (int c = 0; c < 6; ++c) pc[r][c] += __shfl_xor(pc[r][c], msk);
        }
        if (cl == 0) {
            #pragma unroll
            for (int c = 0; c < 6; ++c) comb[w][quad * 4 + r][c] = pc[r][c];
        }
    }
    __syncthreads();
    // combine halves + store: 192 entries (2 row-groups x 16 rows x 6 cols)
    if (tid < 192) {
        int rgg = tid / 96;
        int rem = tid % 96;
        int rr = rem / 6, c = rem % 6;
        int row = blockIdx.x * 32 + rgg * 16 + rr;
        if (row < M)
            out[(size_t)row * 6 + c] = comb[rgg * 2][rr][c] + comb[rgg * 2 + 1][rr][c] + b2[c];
    }
}

// one wave per dst node. Pass 1 (64-lane edge-parallel): score->LDS, max, exp->LDS, sum
// (register fast path for deg<=64). Pass 2: 16-lane group per edge, half8 gathers, 4x unroll.
__global__ __launch_bounds__(256) void k_aggregate(const _Float16* __restrict__ hh, const int* __restrict__ off,
                                                   const int* __restrict__ csrc, const float* __restrict__ avs,
                                                   const float* __restrict__ avd, const float* __restrict__ bias,
                                                   _Float16* __restrict__ outh, int n) {
    __shared__ float ew[4][DCAP];
    int wv = threadIdx.x >> 6;
    int w = (blockIdx.x * 256 + threadIdx.x) >> 6;
    int lane = threadIdx.x & 63;
    if (w >= n) return;
    int grp = lane >> 4;
    int gl = lane & 15;
    int beg = off[w], end = off[w + 1];
    int deg = end - beg;
    float adn = avd[w];
    float accf[8] = {};
    float ssum = 0.f;

    if (deg <= DCAP) {
        if (deg <= 64) {
            int j = beg + lane;
            float sc = -1e30f;
            if (j < end) {
                sc = avs[csrc[j]] + adn;
                sc = (sc < 0.f) ? 0.2f * sc : sc;
            }
            float m = sc;
            #pragma unroll
            for (int d = 32; d > 0; d >>= 1) m = fmaxf(m, __shfl_xor(m, d));
            float e = 0.f;
            if (j < end) {
                e = __expf(sc - m);
                ew[wv][lane] = e;
            }
            float ss = e;
            #pragma unroll
            for (int d = 32; d > 0; d >>= 1) ss += __shfl_xor(ss, d);
            ssum = ss;
        } else {
            float m = -1e30f;
            for (int j = beg + lane; j < end; j += 64) {
                float sc = avs[csrc[j]] + adn;
                sc = (sc < 0.f) ? 0.2f * sc : sc;
                ew[wv][j - beg] = sc;
                m = fmaxf(m, sc);
            }
            #pragma unroll
            for (int d = 32; d > 0; d >>= 1) m = fmaxf(m, __shfl_xor(m, d));
            float ss = 0.f;
            for (int j = beg + lane; j < end; j += 64) {
                float e = __expf(ew[wv][j - beg] - m);
                ew[wv][j - beg] = e;
                ss += e;
            }
            #pragma unroll
            for (int d = 32; d > 0; d >>= 1) ss += __shfl_xor(ss, d);
            ssum = ss;
        }
        int j = beg + grp;
        for (; j + 12 < end; j += 16) {
            int s0 = csrc[j], s1 = csrc[j + 4], s2 = csrc[j + 8], s3 = csrc[j + 12];
            half8 v0 = *((const half8*)(hh + (size_t)s0 * 128) + gl);
            half8 v1 = *((const half8*)(hh + (size_t)s1 * 128) + gl);
            half8 v2 = *((const half8*)(hh + (size_t)s2 * 128) + gl);
            half8 v3 = *((const half8*)(hh + (size_t)s3 * 128) + gl);
            float e0 = ew[wv][j - beg],     e1 = ew[wv][j + 4 - beg];
            float e2 = ew[wv][j + 8 - beg], e3 = ew[wv][j + 12 - beg];
            #pragma unroll
            for (int f = 0; f < 8; ++f)
                accf[f] += (e0 * (float)v0[f] + e1 * (float)v1[f])
                         + (e2 * (float)v2[f] + e3 * (float)v3[f]);
        }
        for (; j < end; j += 4) {
            int s0 = csrc[j];
            half8 v0 = *((const half8*)(hh + (size_t)s0 * 128) + gl);
            float e0 = ew[wv][j - beg];
            #pragma unroll
            for (int f = 0; f < 8; ++f) accf[f] += e0 * (float)v0[f];
        }
    } else {
        float m = -1e30f;
        for (int j = beg + lane; j < end; j += 64) {
            float sc = avs[csrc[j]] + adn;
            sc = (sc < 0.f) ? 0.2f * sc : sc;
            m = fmaxf(m, sc);
        }
        #pragma unroll
        for (int d = 32; d > 0; d >>= 1) m = fmaxf(m, __shfl_xor(m, d));
        float ss = 0.f;
        for (int j = beg + grp; j < end; j += 4) {
            int s0 = csrc[j];
            half8 v0 = *((const half8*)(hh + (size_t)s0 * 128) + gl);
            float sc = avs[s0] + adn; sc = (sc < 0.f) ? 0.2f * sc : sc;
            float e0 = __expf(sc - m);
            ss += e0;
            #pragma unroll
            for (int f = 0; f < 8; ++f) accf[f] += e0 * (float)v0[f];
        }
        ssum = ss;
    }
    #pragma unroll
    for (int f = 0; f < 8; ++f) {
        accf[f] += __shfl_xor(accf[f], 16);
        accf[f] += __shfl_xor(accf[f], 32);
    }
    if (deg > DCAP) {
        ssum += __shfl_xor(ssum, 16);
        ssum += __shfl_xor(ssum, 32);
    }
    if (grp == 0) {
        float inv = 1.f / ssum;
        float4 b0 = ((const float4*)bias)[gl * 2];
        float4 b1 = ((const float4*)bias)[gl * 2 + 1];
        half8 o;
        o[0] = (_Float16)fmaxf(accf[0] * inv + b0.x, 0.f);
        o[1] = (_Float16)fmaxf(accf[1] * inv + b0.y, 0.f);
        o[2] = (_Float16)fmaxf(accf[2] * inv + b0.z, 0.f);
        o[3] = (_Float16)fmaxf(accf[3] * inv + b0.w, 0.f);
        o[4] = (_Float16)fmaxf(accf[4] * inv + b1.x, 0.f);
        o[5] = (_Float16)fmaxf(accf[5] * inv + b1.y, 0.f);
        o[6] = (_Float16)fmaxf(accf[6] * inv + b1.z, 0.f);
        o[7] = (_Float16)fmaxf(accf[7] * inv + b1.w, 0.f);
        *((half8*)(outh + (size_t)w * 128) + gl) = o;
    }
}

extern "C" void kernel_launch(void* const* d_in, const int* in_sizes, int n_in,
                              void* d_out, int out_size, void* d_ws, size_t ws_size,
                              hipStream_t stream) {
    const float* x   = (const float*)d_in[0];
    const int*   ei  = (const int*)d_in[1];
    const float* W[3]    = {(const float*)d_in[2], (const float*)d_in[6], (const float*)d_in[10]};
    const float* bL[3]   = {(const float*)d_in[3], (const float*)d_in[7], (const float*)d_in[11]};
    const float* asr[3]  = {(const float*)d_in[4], (const float*)d_in[8], (const float*)d_in[12]};
    const float* ads[3]  = {(const float*)d_in[5], (const float*)d_in[9], (const float*)d_in[13]};
    const float* Wm1 = (const float*)d_in[14];
    const float* bm1 = (const float*)d_in[15];
    const float* Wm2 = (const float*)d_in[16];
    const float* bm2 = (const float*)d_in[17];
    float* out = (float*)d_out;

    const int N_ = in_sizes[0] / 128;
    const int E_ = in_sizes[1] / 2;
    const int TOT = E_ + N_;
    const int NB = (N_ + 255) / 256;

    char* p = (char*)d_ws;
    auto alloc = [&](size_t bytes) { void* r = (void*)p; p += (bytes + 255) & ~(size_t)255; return r; };
    size_t npad = ((size_t)N_ * 4 + 255) & ~(size_t)255;
    int*   deg  = (int*)alloc(npad);
    int*   off  = (int*)alloc((size_t)(N_ + 1) * 4);
    int*   bsum = (int*)alloc((size_t)(NB + 1) * 4);
    int*   rank = (int*)alloc((size_t)TOT * 4);
    int*   csrc = (int*)alloc((size_t)TOT * 4);
    float* avs  = (float*)alloc((size_t)N_ * 4);
    float* avd  = (float*)alloc((size_t)N_ * 4);
    _Float16* Wt3  = (_Float16*)alloc(3 * 16384 * 2);
    _Float16* Wm1t = (_Float16*)alloc(32768 * 2);
    _Float16* xh   = (_Float16*)alloc((size_t)N_ * 128 * 2);
    _Float16* agg  = (_Float16*)alloc((size_t)N_ * 128 * 2);
    _Float16* hh   = (_Float16*)alloc((size_t)N_ * 128 * 2);

    // ---- CSR build + prep ----
    hipMemsetAsync(deg, 0, npad, stream);
    k_hist<<<(TOT + 255) / 256, 256, 0, stream>>>(ei, deg, rank, E_, N_);
    k_bsum<<<NB, 256, 0, stream>>>(deg, bsum, N_);
    k_scanb<<<1, 256, 0, stream>>>(bsum, NB);
    k_off<<<NB, 256, 0, stream>>>(deg, bsum, off, N_);
    k_scatter<<<(TOT + 255) / 256, 256, 0, stream>>>(ei, off, rank, csrc, E_, N_);
    int n4 = N_ * 32;
    int prep_items = n4 + 3 * 16384 + 32768;
    k_prep<<<(prep_items + 255) / 256, 256, 0, stream>>>(x, xh, W[0], W[1], W[2], Wt3, Wm1, Wm1t, n4);

    const int wave_blocks = (N_ + 3) / 4;
    const int gat_blocks = (N_ + 63) / 64;

    // ---- 3 GAT layers ----
    const _Float16* cur_in = xh;
    for (int l = 0; l < 3; ++l) {
        k_mfma_gat<<<gat_blocks, 256, 0, stream>>>(cur_in, Wt3 + l * 16384, asr[l], ads[l],
                                                   hh, avs, avd, N_);
        k_aggregate<<<wave_blocks, 256, 0, stream>>>(hh, off, csrc, avs, avd, bL[l], agg, N_);
        cur_in = agg;
    }

    // ---- fused MLP head (acc[8], no atomics, no spill) ----
    k_mfma_mlp<<<(N_ + 31) / 32, 256, 0, stream>>>(agg, Wm1t, bm1, Wm2, bm2, out, N_);
}